// Round 4
// baseline (485.247 us; speedup 1.0000x reference)
//
#include <hip/hip_runtime.h>
#include <hip/hip_bf16.h>

typedef __attribute__((ext_vector_type(8))) short bf16x8;
typedef __attribute__((ext_vector_type(4))) float f32x4;
typedef __attribute__((ext_vector_type(16))) float f32x16;
typedef unsigned int u32;
typedef unsigned short ush;

#define SEQ 1024
#define MTOT 4096   // B*S
#define QSCALE_LOG2 0.18033688f   // log2(e)/8

#if __has_builtin(__builtin_amdgcn_exp2f)
#define EXP2(x) __builtin_amdgcn_exp2f(x)
#else
#define EXP2(x) exp2f(x)
#endif

__device__ __forceinline__ ush f2bf(float f){
  u32 u = __float_as_uint(f);
  u32 r = (u + 0x7fffu + ((u >> 16) & 1u)) >> 16;
  return (ush)r;
}

__device__ __forceinline__ f32x4 mfma16(bf16x8 a, bf16x8 b, f32x4 c){
  return __builtin_amdgcn_mfma_f32_16x16x32_bf16(a, b, c, 0, 0, 0);
}
__device__ __forceinline__ f32x16 mfma32(bf16x8 a, bf16x8 b, f32x16 c){
  return __builtin_amdgcn_mfma_f32_32x32x16_bf16(a, b, c, 0, 0, 0);
}

__device__ __forceinline__ u32 cvtpk(float lo, float hi){
  u32 r; asm("v_cvt_pk_bf16_f32 %0, %1, %2" : "=v"(r) : "v"(lo), "v"(hi)); return r;
}

__device__ __forceinline__ void gload_lds16(const ush* g, ush* l){
  __builtin_amdgcn_global_load_lds(
      (const __attribute__((address_space(1))) u32*)g,
      (__attribute__((address_space(3))) u32*)l, 16, 0, 0);
}

// ---------------- elementwise convert f32 -> bf16 ----------------
__global__ __launch_bounds__(256) void cvt_kernel(const float* __restrict__ src,
                                                  ush* __restrict__ dst, int n){
  int i = (blockIdx.x * 256 + threadIdx.x) * 4;
  if (i < n){
    float4 v = *(const float4*)&src[i];
    ushort4 o = { f2bf(v.x), f2bf(v.y), f2bf(v.z), f2bf(v.w) };
    *(ushort4*)&dst[i] = o;
  }
}

// ---------------- transpose + convert: dst[c][r] = bf16(src[r][c]) ----------------
__global__ __launch_bounds__(256) void tconv_kernel(const float* __restrict__ src,
                                                    ush* __restrict__ dst, int R, int C){
  __shared__ float t[32][33];
  int tx = threadIdx.x & 31, ty = threadIdx.x >> 5;
  int r0 = blockIdx.y * 32, c0 = blockIdx.x * 32;
  #pragma unroll
  for (int i = 0; i < 32; i += 8)
    t[ty + i][tx] = src[(size_t)(r0 + ty + i) * C + (c0 + tx)];
  __syncthreads();
  #pragma unroll
  for (int i = 0; i < 32; i += 8)
    dst[(size_t)(c0 + ty + i) * R + (r0 + tx)] = f2bf(t[tx][ty + i]);
}

__global__ __launch_bounds__(256) void biaspack_kernel(const float* __restrict__ bq,
    const float* __restrict__ bk, const float* __restrict__ bv, float* __restrict__ dst){
  int i = blockIdx.x * 256 + threadIdx.x;
  if (i < 3072){
    float v = (i < 1024) ? bq[i] : (i < 2048) ? bk[i - 1024] : bv[i - 2048];
    dst[i] = v;
  }
}

// ---------------- V transpose: VT[bh*64+d][key] = qkv[b*S+key][2048+h*64+d] ----------------
__global__ __launch_bounds__(256) void vtrans_kernel(const ush* __restrict__ qkv,
                                                     ush* __restrict__ VT){
  __shared__ ush t[32][34];
  int tx = threadIdx.x & 31, ty = threadIdx.x >> 5;   // ty 0..7
  int bh = blockIdx.z, b = bh >> 4, h = bh & 15;
  int k0 = blockIdx.x * 32, d0 = blockIdx.y * 32;
  #pragma unroll
  for (int i = 0; i < 32; i += 8)
    t[ty + i][tx] = qkv[(size_t)(b * SEQ + k0 + ty + i) * 3072 + 2048 + h * 64 + d0 + tx];
  __syncthreads();
  #pragma unroll
  for (int i = 0; i < 32; i += 8)
    VT[(size_t)(bh * 64 + d0 + ty + i) * SEQ + k0 + tx] = t[tx][ty + i];
}

// =====================================================================
// 256x256 8-phase GEMM (unchanged from round 3)
// =====================================================================
__device__ __forceinline__ void stage_piece(ush* piece, const ush* g0, int K,
                                            int tid, int w){
  #pragma unroll
  for (int I = 0; I < 2; I++){
    int c = I * 512 + tid;
    int r = c >> 2;
    int gl = (c & 3) ^ ((r >> 1) & 3);
    gload_lds16(g0 + (size_t)r * K + gl * 8, piece + I * 4096 + w * 512);
  }
}

__device__ __forceinline__ bf16x8 frag(const ush* piece, int row, int g){
  int phys = g ^ ((row >> 1) & 3);
  return *(const bf16x8*)(piece + row * 32 + phys * 8);
}

#define PH_BAR_TOP() do{ __builtin_amdgcn_sched_barrier(0); \
  __builtin_amdgcn_s_barrier(); \
  asm volatile("s_waitcnt lgkmcnt(0)" ::: "memory"); \
  __builtin_amdgcn_sched_barrier(0); \
  __builtin_amdgcn_s_setprio(1); }while(0)
#define PH_BAR_BOT() do{ __builtin_amdgcn_s_setprio(0); \
  __builtin_amdgcn_sched_barrier(0); \
  __builtin_amdgcn_s_barrier(); }while(0)

template<int RELU, int OUTF32, int SCALEQ>
__global__ __launch_bounds__(512, 2) void gemm8_kernel(
    const ush* __restrict__ A, const ush* __restrict__ Bt,
    const float* __restrict__ bias,
    ush* __restrict__ Cb, float* __restrict__ Cf,
    int M, int N, int K, int ldc, int ksl)
{
  __shared__ ush lds[2][2][2][8192];   // [buf][A/B][ks][16KB piece]
  const int tid = threadIdx.x;
  const int lane = tid & 63, w = tid >> 6;
  const int g = lane >> 4, qr = lane & 15;
  const int wr = w >> 2, wc = w & 3;
  const int gx = gridDim.x;
  const int nwg = gx * gridDim.y;
  const int id = blockIdx.y * gx + blockIdx.x;
  const int swz = (id & 7) * (nwg >> 3) + (id >> 3);
  const int bn = (swz % gx) * 256;
  const int bm = (swz / gx) * 256;
  const int kbase = blockIdx.z * ksl;
  const int NT = ksl >> 6;
  const ush* Ab = A  + (size_t)bm * K + kbase;
  const ush* Bb = Bt + (size_t)bn * K + kbase;

  stage_piece(lds[0][0][0], Ab,      K, tid, w);
  stage_piece(lds[0][1][0], Bb,      K, tid, w);
  stage_piece(lds[0][0][1], Ab + 32, K, tid, w);
  stage_piece(lds[0][1][1], Bb + 32, K, tid, w);
  if (NT > 1){
    stage_piece(lds[1][0][0], Ab + 64, K, tid, w);
    stage_piece(lds[1][1][0], Bb + 64, K, tid, w);
  }
  asm volatile("s_waitcnt vmcnt(4)" ::: "memory");
  __builtin_amdgcn_sched_barrier(0);
  __builtin_amdgcn_s_barrier();

  f32x4 acc[8][4] = {};
  const int ar = wr * 128 + qr;
  const int br = wc * 64 + qr;

  for (int T = 0; T < NT; ++T){
    const int cb = T & 1, nb = cb ^ 1;
    const ush* An = Ab + (size_t)(T + 1) * 64;
    const ush* Bn = Bb + (size_t)(T + 1) * 64;
    const ush* Af = Ab + (size_t)(T + 2) * 64;
    const ush* Bf = Bb + (size_t)(T + 2) * 64;
    bf16x8 af[4], bfr[4];

    #pragma unroll
    for (int j = 0; j < 4; j++) bfr[j] = frag(lds[cb][1][0], br + j * 16, g);
    #pragma unroll
    for (int i = 0; i < 4; i++) af[i] = frag(lds[cb][0][0], ar + i * 16, g);
    if (T + 1 < NT) stage_piece(lds[nb][0][1], An + 32, K, tid, w);
    PH_BAR_TOP();
    #pragma unroll
    for (int i = 0; i < 4; i++)
      #pragma unroll
      for (int j = 0; j < 4; j++)
        acc[i][j] = mfma16(af[i], bfr[j], acc[i][j]);
    PH_BAR_BOT();

    #pragma unroll
    for (int i = 0; i < 4; i++) af[i] = frag(lds[cb][0][0], ar + 64 + i * 16, g);
    if (T + 1 < NT) stage_piece(lds[nb][1][1], Bn + 32, K, tid, w);
    PH_BAR_TOP();
    #pragma unroll
    for (int i = 0; i < 4; i++)
      #pragma unroll
      for (int j = 0; j < 4; j++)
        acc[4 + i][j] = mfma16(af[i], bfr[j], acc[4 + i][j]);
    PH_BAR_BOT();

    #pragma unroll
    for (int j = 0; j < 4; j++) bfr[j] = frag(lds[cb][1][1], br + j * 16, g);
    #pragma unroll
    for (int i = 0; i < 4; i++) af[i] = frag(lds[cb][0][1], ar + i * 16, g);
    if (T + 2 < NT) stage_piece(lds[cb][0][0], Af, K, tid, w);
    PH_BAR_TOP();
    #pragma unroll
    for (int i = 0; i < 4; i++)
      #pragma unroll
      for (int j = 0; j < 4; j++)
        acc[i][j] = mfma16(af[i], bfr[j], acc[i][j]);
    PH_BAR_BOT();

    #pragma unroll
    for (int i = 0; i < 4; i++) af[i] = frag(lds[cb][0][1], ar + 64 + i * 16, g);
    if (T + 2 < NT) stage_piece(lds[cb][1][0], Bf, K, tid, w);
    PH_BAR_TOP();
    #pragma unroll
    for (int i = 0; i < 4; i++)
      #pragma unroll
      for (int j = 0; j < 4; j++)
        acc[4 + i][j] = mfma16(af[i], bfr[j], acc[4 + i][j]);
    __builtin_amdgcn_s_setprio(0);
    __builtin_amdgcn_sched_barrier(0);
    asm volatile("s_waitcnt vmcnt(4)" ::: "memory");
    __builtin_amdgcn_sched_barrier(0);
    __builtin_amdgcn_s_barrier();
  }

  float* Cfz = Cf;
  if (OUTF32) Cfz = Cf + (size_t)blockIdx.z * M * ldc;
  #pragma unroll
  for (int j = 0; j < 4; j++){
    const int col = bn + wc * 64 + j * 16 + qr;
    const float bv = OUTF32 ? 0.f : bias[col];
    const float scl = (SCALEQ && col < 1024) ? QSCALE_LOG2 : 1.f;
    #pragma unroll
    for (int i = 0; i < 8; i++){
      const int row0 = bm + wr * 128 + i * 16 + g * 4;
      #pragma unroll
      for (int rr = 0; rr < 4; rr++){
        float v = acc[i][j][rr] + bv;
        if (RELU) v = fmaxf(v, 0.f);
        if (SCALEQ) v *= scl;
        const size_t idx = (size_t)(row0 + rr) * ldc + col;
        if (OUTF32) Cfz[idx] = v; else Cb[idx] = f2bf(v);
      }
    }
  }
}

// =====================================================================
// Flash attention v3: split-KV x2, LDS-free, 32x32x16 MFMA, swapped QK^T,
// in-register softmax (tree reduce + cvt_pk + permlane32_swap), exp2 domain.
// grid: (S/128, 2 kv-splits, B*H), block 256 (4 warps x 32 q-rows each).
// Writes un-normalized O (f32) + (m,l) per split; combine kernel merges.
// =====================================================================
__global__ __launch_bounds__(256, 4) void attn2_kernel(
    const ush* __restrict__ qkv, const ush* __restrict__ VT,
    const int* __restrict__ mask, float* __restrict__ Opart,
    float* __restrict__ ml)
{
  const int tid = threadIdx.x;
  const int lane = tid & 63, w = tid >> 6;
  const int c = lane & 31, hi = lane >> 5;
  const int bh = blockIdx.z, b = bh >> 4, hh = bh & 15;
  const int split = blockIdx.y;
  const int kbeg = split * 512;
  const int q0 = blockIdx.x * 128 + w * 32;

  __shared__ int mflag;
  if (tid == 0) mflag = 1;
  __syncthreads();
  {
    int4 mv = *(const int4*)&mask[b * SEQ + tid * 4];
    if (!(mv.x && mv.y && mv.z && mv.w)) mflag = 0;
  }
  __syncthreads();
  const bool maskall = (mflag != 0);

  const ush* Qrow = qkv + (size_t)(b * SEQ + q0 + c) * 3072 + hh * 64;
  bf16x8 qf[4];
  #pragma unroll
  for (int kd = 0; kd < 4; kd++)
    qf[kd] = *(const bf16x8*)(Qrow + kd * 16 + hi * 8);

  const ush* Kb  = qkv + (size_t)(b * SEQ) * 3072 + 1024 + hh * 64;
  const ush* VTb = VT + (size_t)(bh * 64) * SEQ;

  f32x16 o0 = {}, o1 = {};
  float m_run = -1e30f, l_run = 0.f;

  bf16x8 kf[8];
  #pragma unroll
  for (int kb = 0; kb < 2; kb++)
    #pragma unroll
    for (int kd = 0; kd < 4; kd++)
      kf[kb * 4 + kd] = *(const bf16x8*)(Kb + (size_t)(kbeg + kb * 32 + c) * 3072 + kd * 16 + hi * 8);

  for (int t = 0; t < 8; ++t){
    const int k0 = kbeg + t * 64;
    bf16x8 vf[8];
    #pragma unroll
    for (int db = 0; db < 2; db++)
      #pragma unroll
      for (int ks = 0; ks < 4; ks++)
        vf[db * 4 + ks] = *(const bf16x8*)(VTb + (size_t)(db * 32 + c) * SEQ + k0 + ks * 16 + hi * 8);

    f32x16 s0 = {}, s1 = {};
    __builtin_amdgcn_s_setprio(1);
    #pragma unroll
    for (int kd = 0; kd < 4; kd++){
      s0 = mfma32(kf[kd],     qf[kd], s0);
      s1 = mfma32(kf[4 + kd], qf[kd], s1);
    }
    __builtin_amdgcn_s_setprio(0);

    float p[32];
    #pragma unroll
    for (int r = 0; r < 16; r++){ p[r] = s0[r]; p[16 + r] = s1[r]; }

    if (!maskall){
      #pragma unroll
      for (int r32 = 0; r32 < 32; r32++){
        int r = r32 & 15;
        int key = (r32 >> 4) * 32 + (r & 3) + 8 * (r >> 2) + 4 * hi;
        if (mask[b * SEQ + k0 + key] == 0) p[r32] = -1e9f;
      }
    }

    // prefetch K frags for next tile (lands under softmax)
    if (t + 1 < 8){
      #pragma unroll
      for (int kb = 0; kb < 2; kb++)
        #pragma unroll
        for (int kd = 0; kd < 4; kd++)
          kf[kb * 4 + kd] = *(const bf16x8*)(Kb + (size_t)(k0 + 64 + kb * 32 + c) * 3072 + kd * 16 + hi * 8);
    }

    // tree max (depth 5 + 1 shuffle)
    float tm[16];
    #pragma unroll
    for (int r = 0; r < 16; r++) tm[r] = fmaxf(p[r], p[r + 16]);
    #pragma unroll
    for (int s = 8; s >= 1; s >>= 1)
      #pragma unroll
      for (int r = 0; r < s; r++) tm[r] = fmaxf(tm[r], tm[r + s]);
    float pmax = fmaxf(tm[0], __shfl_xor(tm[0], 32));

    if (__any(pmax > m_run + 8.f)){
      float m_new = fmaxf(m_run, pmax);
      float corr = EXP2(m_run - m_new);
      l_run *= corr;
      m_run = m_new;
      #pragma unroll
      for (int r = 0; r < 16; r++){
        float cr = __shfl(corr, (r & 3) + 8 * (r >> 2) + 4 * hi);
        o0[r] *= cr; o1[r] *= cr;
      }
    }

    // exp + tree sum
    float ts[16];
    #pragma unroll
    for (int r = 0; r < 16; r++){
      p[r]      = EXP2(p[r] - m_run);
      p[r + 16] = EXP2(p[r + 16] - m_run);
      ts[r] = p[r] + p[r + 16];
    }
    #pragma unroll
    for (int s = 8; s >= 1; s >>= 1)
      #pragma unroll
      for (int r = 0; r < s; r++) ts[r] += ts[r + s];
    l_run += ts[0] + __shfl_xor(ts[0], 32);

    // P -> bf16 A-frags: 16 cvt_pk + 8 permlane32_swap
    union { u32 wdw[4]; bf16x8 v; } af[4];
    #pragma unroll
    for (int ks = 0; ks < 4; ks++){
      int b0 = (ks >> 1) * 16 + 8 * (ks & 1);
      u32 c00 = cvtpk(p[b0],     p[b0 + 1]);
      u32 c01 = cvtpk(p[b0 + 2], p[b0 + 3]);
      u32 c10 = cvtpk(p[b0 + 4], p[b0 + 5]);
      u32 c11 = cvtpk(p[b0 + 6], p[b0 + 7]);
      asm volatile("v_permlane32_swap_b32 %0, %1" : "+v"(c10), "+v"(c00));
      asm volatile("v_permlane32_swap_b32 %0, %1" : "+v"(c11), "+v"(c01));
      af[ks].wdw[0] = c00; af[ks].wdw[1] = c01; af[ks].wdw[2] = c10; af[ks].wdw[3] = c11;
    }

    __builtin_amdgcn_s_setprio(1);
    #pragma unroll
    for (int ks = 0; ks < 4; ks++){
      o0 = mfma32(af[ks].v, vf[ks],     o0);
      o1 = mfma32(af[ks].v, vf[4 + ks], o1);
    }
    __builtin_amdgcn_s_setprio(0);
  }

  // epilogue: un-normalized O + (m,l)
  if (lane < 32){
    float2* mlp = (float2*)ml;
    mlp[((size_t)split * 64 + bh) * SEQ + q0 + c] = make_float2(m_run, l_run);
  }
  #pragma unroll
  for (int r = 0; r < 16; r++){
    int crow = (r & 3) + 8 * (r >> 2) + 4 * hi;
    size_t base = (size_t)split * MTOT * 1024 + (size_t)(b * SEQ + q0 + crow) * 1024 + hh * 64;
    Opart[base + c]      = o0[r];
    Opart[base + 32 + c] = o1[r];
  }
}

// ---------------- split-KV combine: ctx = (O0*w0 + O1*w1) / (l0*w0 + l1*w1) ----------------
__global__ __launch_bounds__(256) void attn_combine_kernel(
    const float* __restrict__ Opart, const float* __restrict__ ml,
    ush* __restrict__ ctx)
{
  const int row = blockIdx.x;            // b*S + q
  const int b = row >> 10, q = row & 1023;
  const int col = threadIdx.x * 4;
  const int hh = col >> 6;
  const int bh = b * 16 + hh;
  const float2* mlp = (const float2*)ml;
  float2 a0 = mlp[(size_t)bh * SEQ + q];
  float2 a1 = mlp[((size_t)64 + bh) * SEQ + q];
  float m = fmaxf(a0.x, a1.x);
  float w0 = EXP2(a0.x - m), w1 = EXP2(a1.x - m);
  float li = 1.f / fmaxf(a0.y * w0 + a1.y * w1, 1e-30f);
  size_t base = (size_t)row * 1024 + col;
  float4 u = *(const float4*)&Opart[base];
  float4 v = *(const float4*)&Opart[(size_t)MTOT * 1024 + base];
  ushort4 o;
  o.x = f2bf((u.x * w0 + v.x * w1) * li);
  o.y = f2bf((u.y * w0 + v.y * w1) * li);
  o.z = f2bf((u.z * w0 + v.z * w1) * li);
  o.w = f2bf((u.w * w0 + v.w * w1) * li);
  *(ushort4*)&ctx[base] = o;
}

// -------- residual + 4-way split-K reduce + bias + LayerNorm --------
template<bool WB>
__global__ __launch_bounds__(256) void ln4_kernel(
    const float* __restrict__ X, const float* __restrict__ P,
    const float* __restrict__ bias,
    const float* __restrict__ gam, const float* __restrict__ bet,
    float* __restrict__ Of, ush* __restrict__ Ob)
{
  const int row = blockIdx.x, tid = threadIdx.x;
  const size_t base = (size_t)row * 1024 + tid * 4;
  float4 xv = *(const float4*)&X[base];
  float4 bv4 = *(const float4*)&bias[tid * 4];
  float s0 = xv.x + bv4.x, s1 = xv.y + bv4.y, s2 = xv.z + bv4.z, s3 = xv.w + bv4.w;
  #pragma unroll
  for (int z = 0; z < 4; z++){
    float4 p = *(const float4*)&P[(size_t)z * 4194304 + base];
    s0 += p.x; s1 += p.y; s2 += p.z; s3 += p.w;
  }
  float sum = s0 + s1 + s2 + s3;
  float sq  = s0 * s0 + s1 * s1 + s2 * s2 + s3 * s3;
  #pragma unroll
  for (int o = 1; o < 64; o <<= 1){ sum += __shfl_xor(sum, o); sq += __shfl_xor(sq, o); }
  __shared__ float red[8];
  int lane = tid & 63, w = tid >> 6;
  if (lane == 0){ red[w] = sum; red[4 + w] = sq; }
  __syncthreads();
  sum = red[0] + red[1] + red[2] + red[3];
  sq  = red[4] + red[5] + red[6] + red[7];
  float mean = sum * (1.f / 1024.f);
  float var  = sq * (1.f / 1024.f) - mean * mean;
  float rs = rsqrtf(var + 1e-5f);
  float4 gv = *(const float4*)&gam[tid * 4];
  float4 bt = *(const float4*)&bet[tid * 4];
  float o0 = (s0 - mean) * rs * gv.x + bt.x;
  float o1 = (s1 - mean) * rs * gv.y + bt.y;
  float o2 = (s2 - mean) * rs * gv.z + bt.z;
  float o3 = (s3 - mean) * rs * gv.w + bt.w;
  float4 ov = { o0, o1, o2, o3 };
  *(float4*)&Of[base] = ov;
  if (WB){
    ushort4 ob = { f2bf(o0), f2bf(o1), f2bf(o2), f2bf(o3) };
    *(ushort4*)&Ob[base] = ob;
  }
}

// ---------------- orchestration ----------------
extern "C" void kernel_launch(void* const* d_in, const int* in_sizes, int n_in,
                              void* d_out, int out_size, void* d_ws, size_t ws_size,
                              hipStream_t stream)
{
  const float* x    = (const float*)d_in[0];
  const int*   mask = (const int*)  d_in[1];
  const float* Wq = (const float*)d_in[2];
  const float* bq = (const float*)d_in[3];
  const float* Wk = (const float*)d_in[4];
  const float* bk = (const float*)d_in[5];
  const float* Wv = (const float*)d_in[6];
  const float* bv = (const float*)d_in[7];
  const float* Wo = (const float*)d_in[8];
  const float* bo = (const float*)d_in[9];
  const float* W1 = (const float*)d_in[10];
  const float* b1 = (const float*)d_in[11];
  const float* W2 = (const float*)d_in[12];
  const float* b2 = (const float*)d_in[13];
  const float* g1 = (const float*)d_in[14];
  const float* be1= (const float*)d_in[15];
  const float* g2 = (const float*)d_in[16];
  const float* be2= (const float*)d_in[17];
  float* out = (float*)d_out;

  char* ws = (char*)d_ws;
  size_t off = 0;
  auto alloc = [&](size_t bytes)->void*{ void* p = ws + off; off += (bytes + 255) & ~(size_t)255; return p; };
  ush* xb     = (ush*)alloc((size_t)MTOT * 1024 * 2);
  ush* wqkvT  = (ush*)alloc((size_t)3072 * 1024 * 2);
  ush* woT    = (ush*)alloc((size_t)1024 * 1024 * 2);
  ush* w1T    = (ush*)alloc((size_t)4096 * 1024 * 2);
  ush* w2T    = (ush*)alloc((size_t)1024 * 4096 * 2);
  float* bqkv = (float*)alloc(3072 * 4);
  ush* qkv    = (ush*)alloc((size_t)MTOT * 3072 * 2);   // reused (with ctx) as ff1
  ush* ctx    = (ush*)alloc((size_t)MTOT * 1024 * 2);
  float* part = (float*)alloc((size_t)4 * MTOT * 1024 * 4);  // split-K partials (64MB)
  float* h    = (float*)alloc((size_t)MTOT * 1024 * 4);
  ush* hb     = (ush*)alloc((size_t)MTOT * 1024 * 2);
  ush* VT     = (ush*)alloc((size_t)64 * 64 * SEQ * 2);      // V^T per (b,h)
  ush* ff1    = qkv;   // 32 MB span (qkv 24MB + ctx 8MB), both dead by then
  // attention split-KV scratch aliases onto `part` (dead until Wo GEMM):
  float* Opart = part;                                        // 32 MB (2 splits)
  float* mlbuf = part + (size_t)2 * MTOT * 1024;              // 1 MB

  // 1. converts / transposes
  cvt_kernel<<<dim3(4096), dim3(256), 0, stream>>>(x, xb, MTOT * 1024);
  tconv_kernel<<<dim3(32, 32), dim3(256), 0, stream>>>(Wq, wqkvT,               1024, 1024);
  tconv_kernel<<<dim3(32, 32), dim3(256), 0, stream>>>(Wk, wqkvT + 1024 * 1024, 1024, 1024);
  tconv_kernel<<<dim3(32, 32), dim3(256), 0, stream>>>(Wv, wqkvT + 2048 * 1024, 1024, 1024);
  tconv_kernel<<<dim3(32, 32), dim3(256), 0, stream>>>(Wo, woT,                 1024, 1024);
  tconv_kernel<<<dim3(128, 32), dim3(256), 0, stream>>>(W1, w1T, 1024, 4096);
  tconv_kernel<<<dim3(32, 128), dim3(256), 0, stream>>>(W2, w2T, 4096, 1024);
  biaspack_kernel<<<dim3(12), dim3(256), 0, stream>>>(bq, bk, bv, bqkv);

  // 2. QKV projection (Q pre-scaled by log2e/8 in epilogue)
  gemm8_kernel<0, 0, 1><<<dim3(12, 16, 1), dim3(512), 0, stream>>>(
      xb, wqkvT, bqkv, qkv, nullptr, MTOT, 3072, 1024, 3072, 1024);

  // 3. V transpose for attention B-frags
  vtrans_kernel<<<dim3(32, 2, 64), dim3(256), 0, stream>>>(qkv, VT);

  // 4. attention (split-KV x2) -> Opart/ml, then combine -> ctx
  attn2_kernel<<<dim3(8, 2, 64), dim3(256), 0, stream>>>(qkv, VT, mask, Opart, mlbuf);
  attn_combine_kernel<<<dim3(4096), dim3(256), 0, stream>>>(Opart, mlbuf, ctx);

  // 5. Wo partials: split-K=4, f32 [4][4096][1024]
  gemm8_kernel<0, 1, 0><<<dim3(4, 16, 4), dim3(512), 0, stream>>>(
      ctx, woT, nullptr, nullptr, part, MTOT, 1024, 1024, 1024, 256);

  // 6. h = LN(x + sum(part) + bo)
  ln4_kernel<true><<<dim3(4096), dim3(256), 0, stream>>>(x, part, bo, g1, be1, h, hb);

  // 7. ff1 = relu(h @ W1 + b1) bf16 [4096,4096]
  gemm8_kernel<1, 0, 0><<<dim3(16, 16, 1), dim3(512), 0, stream>>>(
      hb, w1T, b1, ff1, nullptr, MTOT, 4096, 1024, 4096, 1024);

  // 8. FF2 partials: split-K=4 over K=4096
  gemm8_kernel<0, 1, 0><<<dim3(4, 16, 4), dim3(512), 0, stream>>>(
      ff1, w2T, nullptr, nullptr, part, MTOT, 1024, 4096, 1024, 1024);

  // 9. out = LN(h + sum(part) + b2)
  ln4_kernel<false><<<dim3(4096), dim3(256), 0, stream>>>(h, part, b2, g2, be2, out, nullptr);
}

// Round 5
// 419.789 us; speedup vs baseline: 1.1559x; 1.1559x over previous
//
#include <hip/hip_runtime.h>
#include <hip/hip_bf16.h>

typedef __attribute__((ext_vector_type(8))) short bf16x8;
typedef __attribute__((ext_vector_type(4))) float f32x4;
typedef __attribute__((ext_vector_type(16))) float f32x16;
typedef unsigned int u32;
typedef unsigned short ush;

#define SEQ 1024
#define MTOT 4096   // B*S
#define QSCALE_LOG2 0.18033688f   // log2(e)/8

#if __has_builtin(__builtin_amdgcn_exp2f)
#define EXP2(x) __builtin_amdgcn_exp2f(x)
#else
#define EXP2(x) exp2f(x)
#endif

__device__ __forceinline__ ush f2bf(float f){
  u32 u = __float_as_uint(f);
  u32 r = (u + 0x7fffu + ((u >> 16) & 1u)) >> 16;
  return (ush)r;
}

__device__ __forceinline__ f32x4 mfma16(bf16x8 a, bf16x8 b, f32x4 c){
  return __builtin_amdgcn_mfma_f32_16x16x32_bf16(a, b, c, 0, 0, 0);
}
__device__ __forceinline__ f32x16 mfma32(bf16x8 a, bf16x8 b, f32x16 c){
  return __builtin_amdgcn_mfma_f32_32x32x16_bf16(a, b, c, 0, 0, 0);
}

__device__ __forceinline__ u32 cvtpk(float lo, float hi){
  u32 r; asm("v_cvt_pk_bf16_f32 %0, %1, %2" : "=v"(r) : "v"(lo), "v"(hi)); return r;
}

__device__ __forceinline__ void gload_lds16(const ush* g, ush* l){
  __builtin_amdgcn_global_load_lds(
      (const __attribute__((address_space(1))) u32*)g,
      (__attribute__((address_space(3))) u32*)l, 16, 0, 0);
}

// ---------------- elementwise convert f32 -> bf16 ----------------
__global__ __launch_bounds__(256) void cvt_kernel(const float* __restrict__ src,
                                                  ush* __restrict__ dst, int n){
  int i = (blockIdx.x * 256 + threadIdx.x) * 4;
  if (i < n){
    float4 v = *(const float4*)&src[i];
    ushort4 o = { f2bf(v.x), f2bf(v.y), f2bf(v.z), f2bf(v.w) };
    *(ushort4*)&dst[i] = o;
  }
}

// ---------------- transpose + convert: dst[c][r] = bf16(src[r][c]) ----------------
__global__ __launch_bounds__(256) void tconv_kernel(const float* __restrict__ src,
                                                    ush* __restrict__ dst, int R, int C){
  __shared__ float t[32][33];
  int tx = threadIdx.x & 31, ty = threadIdx.x >> 5;
  int r0 = blockIdx.y * 32, c0 = blockIdx.x * 32;
  #pragma unroll
  for (int i = 0; i < 32; i += 8)
    t[ty + i][tx] = src[(size_t)(r0 + ty + i) * C + (c0 + tx)];
  __syncthreads();
  #pragma unroll
  for (int i = 0; i < 32; i += 8)
    dst[(size_t)(c0 + ty + i) * R + (r0 + tx)] = f2bf(t[tx][ty + i]);
}

__global__ __launch_bounds__(256) void biaspack_kernel(const float* __restrict__ bq,
    const float* __restrict__ bk, const float* __restrict__ bv, float* __restrict__ dst){
  int i = blockIdx.x * 256 + threadIdx.x;
  if (i < 3072){
    float v = (i < 1024) ? bq[i] : (i < 2048) ? bk[i - 1024] : bv[i - 2048];
    dst[i] = v;
  }
}

// ---------------- V transpose: VT[bh*64+d][key] = qkv[b*S+key][2048+h*64+d] ----------------
__global__ __launch_bounds__(256) void vtrans_kernel(const ush* __restrict__ qkv,
                                                     ush* __restrict__ VT){
  __shared__ ush t[32][34];
  int tx = threadIdx.x & 31, ty = threadIdx.x >> 5;   // ty 0..7
  int bh = blockIdx.z, b = bh >> 4, h = bh & 15;
  int k0 = blockIdx.x * 32, d0 = blockIdx.y * 32;
  #pragma unroll
  for (int i = 0; i < 32; i += 8)
    t[ty + i][tx] = qkv[(size_t)(b * SEQ + k0 + ty + i) * 3072 + 2048 + h * 64 + d0 + tx];
  __syncthreads();
  #pragma unroll
  for (int i = 0; i < 32; i += 8)
    VT[(size_t)(bh * 64 + d0 + ty + i) * SEQ + k0 + tx] = t[tx][ty + i];
}

// =====================================================================
// 256x256 8-phase GEMM (unchanged from round 3)
// =====================================================================
__device__ __forceinline__ void stage_piece(ush* piece, const ush* g0, int K,
                                            int tid, int w){
  #pragma unroll
  for (int I = 0; I < 2; I++){
    int c = I * 512 + tid;
    int r = c >> 2;
    int gl = (c & 3) ^ ((r >> 1) & 3);
    gload_lds16(g0 + (size_t)r * K + gl * 8, piece + I * 4096 + w * 512);
  }
}

__device__ __forceinline__ bf16x8 frag(const ush* piece, int row, int g){
  int phys = g ^ ((row >> 1) & 3);
  return *(const bf16x8*)(piece + row * 32 + phys * 8);
}

#define PH_BAR_TOP() do{ __builtin_amdgcn_sched_barrier(0); \
  __builtin_amdgcn_s_barrier(); \
  asm volatile("s_waitcnt lgkmcnt(0)" ::: "memory"); \
  __builtin_amdgcn_sched_barrier(0); \
  __builtin_amdgcn_s_setprio(1); }while(0)
#define PH_BAR_BOT() do{ __builtin_amdgcn_s_setprio(0); \
  __builtin_amdgcn_sched_barrier(0); \
  __builtin_amdgcn_s_barrier(); }while(0)

template<int RELU, int OUTF32, int SCALEQ>
__global__ __launch_bounds__(512, 2) void gemm8_kernel(
    const ush* __restrict__ A, const ush* __restrict__ Bt,
    const float* __restrict__ bias,
    ush* __restrict__ Cb, float* __restrict__ Cf,
    int M, int N, int K, int ldc, int ksl)
{
  __shared__ ush lds[2][2][2][8192];   // [buf][A/B][ks][16KB piece]
  const int tid = threadIdx.x;
  const int lane = tid & 63, w = tid >> 6;
  const int g = lane >> 4, qr = lane & 15;
  const int wr = w >> 2, wc = w & 3;
  const int gx = gridDim.x;
  const int nwg = gx * gridDim.y;
  const int id = blockIdx.y * gx + blockIdx.x;
  const int swz = (id & 7) * (nwg >> 3) + (id >> 3);
  const int bn = (swz % gx) * 256;
  const int bm = (swz / gx) * 256;
  const int kbase = blockIdx.z * ksl;
  const int NT = ksl >> 6;
  const ush* Ab = A  + (size_t)bm * K + kbase;
  const ush* Bb = Bt + (size_t)bn * K + kbase;

  stage_piece(lds[0][0][0], Ab,      K, tid, w);
  stage_piece(lds[0][1][0], Bb,      K, tid, w);
  stage_piece(lds[0][0][1], Ab + 32, K, tid, w);
  stage_piece(lds[0][1][1], Bb + 32, K, tid, w);
  if (NT > 1){
    stage_piece(lds[1][0][0], Ab + 64, K, tid, w);
    stage_piece(lds[1][1][0], Bb + 64, K, tid, w);
  }
  asm volatile("s_waitcnt vmcnt(4)" ::: "memory");
  __builtin_amdgcn_sched_barrier(0);
  __builtin_amdgcn_s_barrier();

  f32x4 acc[8][4] = {};
  const int ar = wr * 128 + qr;
  const int br = wc * 64 + qr;

  for (int T = 0; T < NT; ++T){
    const int cb = T & 1, nb = cb ^ 1;
    const ush* An = Ab + (size_t)(T + 1) * 64;
    const ush* Bn = Bb + (size_t)(T + 1) * 64;
    const ush* Af = Ab + (size_t)(T + 2) * 64;
    const ush* Bf = Bb + (size_t)(T + 2) * 64;
    bf16x8 af[4], bfr[4];

    #pragma unroll
    for (int j = 0; j < 4; j++) bfr[j] = frag(lds[cb][1][0], br + j * 16, g);
    #pragma unroll
    for (int i = 0; i < 4; i++) af[i] = frag(lds[cb][0][0], ar + i * 16, g);
    if (T + 1 < NT) stage_piece(lds[nb][0][1], An + 32, K, tid, w);
    PH_BAR_TOP();
    #pragma unroll
    for (int i = 0; i < 4; i++)
      #pragma unroll
      for (int j = 0; j < 4; j++)
        acc[i][j] = mfma16(af[i], bfr[j], acc[i][j]);
    PH_BAR_BOT();

    #pragma unroll
    for (int i = 0; i < 4; i++) af[i] = frag(lds[cb][0][0], ar + 64 + i * 16, g);
    if (T + 1 < NT) stage_piece(lds[nb][1][1], Bn + 32, K, tid, w);
    PH_BAR_TOP();
    #pragma unroll
    for (int i = 0; i < 4; i++)
      #pragma unroll
      for (int j = 0; j < 4; j++)
        acc[4 + i][j] = mfma16(af[i], bfr[j], acc[4 + i][j]);
    PH_BAR_BOT();

    #pragma unroll
    for (int j = 0; j < 4; j++) bfr[j] = frag(lds[cb][1][1], br + j * 16, g);
    #pragma unroll
    for (int i = 0; i < 4; i++) af[i] = frag(lds[cb][0][1], ar + i * 16, g);
    if (T + 2 < NT) stage_piece(lds[cb][0][0], Af, K, tid, w);
    PH_BAR_TOP();
    #pragma unroll
    for (int i = 0; i < 4; i++)
      #pragma unroll
      for (int j = 0; j < 4; j++)
        acc[i][j] = mfma16(af[i], bfr[j], acc[i][j]);
    PH_BAR_BOT();

    #pragma unroll
    for (int i = 0; i < 4; i++) af[i] = frag(lds[cb][0][1], ar + 64 + i * 16, g);
    if (T + 2 < NT) stage_piece(lds[cb][1][0], Bf, K, tid, w);
    PH_BAR_TOP();
    #pragma unroll
    for (int i = 0; i < 4; i++)
      #pragma unroll
      for (int j = 0; j < 4; j++)
        acc[4 + i][j] = mfma16(af[i], bfr[j], acc[4 + i][j]);
    __builtin_amdgcn_s_setprio(0);
    __builtin_amdgcn_sched_barrier(0);
    asm volatile("s_waitcnt vmcnt(4)" ::: "memory");
    __builtin_amdgcn_sched_barrier(0);
    __builtin_amdgcn_s_barrier();
  }

  float* Cfz = Cf;
  if (OUTF32) Cfz = Cf + (size_t)blockIdx.z * M * ldc;
  #pragma unroll
  for (int j = 0; j < 4; j++){
    const int col = bn + wc * 64 + j * 16 + qr;
    const float bv = OUTF32 ? 0.f : bias[col];
    const float scl = (SCALEQ && col < 1024) ? QSCALE_LOG2 : 1.f;
    #pragma unroll
    for (int i = 0; i < 8; i++){
      const int row0 = bm + wr * 128 + i * 16 + g * 4;
      #pragma unroll
      for (int rr = 0; rr < 4; rr++){
        float v = acc[i][j][rr] + bv;
        if (RELU) v = fmaxf(v, 0.f);
        if (SCALEQ) v *= scl;
        const size_t idx = (size_t)(row0 + rr) * ldc + col;
        if (OUTF32) Cfz[idx] = v; else Cb[idx] = f2bf(v);
      }
    }
  }
}

// =====================================================================
// Flash attention v3: split-KV x2, LDS-free, 32x32x16 MFMA, swapped QK^T,
// in-register softmax (tree reduce + cvt_pk + permlane32_swap), exp2 domain.
// grid: (S/128, 2 kv-splits, B*H), block 256 (4 warps x 32 q-rows each).
// launch_bounds(256,3): cap 170 regs -> ~155-reg working set fits (no spill),
// 3 blocks/CU = 12 waves = 37.5% occupancy. (256,4) spilled ~60 regs (R4).
// =====================================================================
__global__ __launch_bounds__(256, 3) void attn2_kernel(
    const ush* __restrict__ qkv, const ush* __restrict__ VT,
    const int* __restrict__ mask, float* __restrict__ Opart,
    float* __restrict__ ml)
{
  const int tid = threadIdx.x;
  const int lane = tid & 63, w = tid >> 6;
  const int c = lane & 31, hi = lane >> 5;
  const int bh = blockIdx.z, b = bh >> 4, hh = bh & 15;
  const int split = blockIdx.y;
  const int kbeg = split * 512;
  const int q0 = blockIdx.x * 128 + w * 32;

  __shared__ int mflag;
  if (tid == 0) mflag = 1;
  __syncthreads();
  {
    int4 mv = *(const int4*)&mask[b * SEQ + tid * 4];
    if (!(mv.x && mv.y && mv.z && mv.w)) mflag = 0;
  }
  __syncthreads();
  const bool maskall = (mflag != 0);

  const ush* Qrow = qkv + (size_t)(b * SEQ + q0 + c) * 3072 + hh * 64;
  bf16x8 qf[4];
  #pragma unroll
  for (int kd = 0; kd < 4; kd++)
    qf[kd] = *(const bf16x8*)(Qrow + kd * 16 + hi * 8);

  const ush* Kb  = qkv + (size_t)(b * SEQ) * 3072 + 1024 + hh * 64;
  const ush* VTb = VT + (size_t)(bh * 64) * SEQ;

  f32x16 o0 = {}, o1 = {};
  float m_run = -1e30f, l_run = 0.f;

  bf16x8 kf[8];
  #pragma unroll
  for (int kb = 0; kb < 2; kb++)
    #pragma unroll
    for (int kd = 0; kd < 4; kd++)
      kf[kb * 4 + kd] = *(const bf16x8*)(Kb + (size_t)(kbeg + kb * 32 + c) * 3072 + kd * 16 + hi * 8);

  for (int t = 0; t < 8; ++t){
    const int k0 = kbeg + t * 64;
    bf16x8 vf[8];
    #pragma unroll
    for (int db = 0; db < 2; db++)
      #pragma unroll
      for (int ks = 0; ks < 4; ks++)
        vf[db * 4 + ks] = *(const bf16x8*)(VTb + (size_t)(db * 32 + c) * SEQ + k0 + ks * 16 + hi * 8);

    f32x16 s0 = {}, s1 = {};
    __builtin_amdgcn_s_setprio(1);
    #pragma unroll
    for (int kd = 0; kd < 4; kd++){
      s0 = mfma32(kf[kd],     qf[kd], s0);
      s1 = mfma32(kf[4 + kd], qf[kd], s1);
    }
    __builtin_amdgcn_s_setprio(0);

    float p[32];
    #pragma unroll
    for (int r = 0; r < 16; r++){ p[r] = s0[r]; p[16 + r] = s1[r]; }

    if (!maskall){
      #pragma unroll
      for (int r32 = 0; r32 < 32; r32++){
        int r = r32 & 15;
        int key = (r32 >> 4) * 32 + (r & 3) + 8 * (r >> 2) + 4 * hi;
        if (mask[b * SEQ + k0 + key] == 0) p[r32] = -1e9f;
      }
    }

    // prefetch K frags for next tile (lands under softmax)
    if (t + 1 < 8){
      #pragma unroll
      for (int kb = 0; kb < 2; kb++)
        #pragma unroll
        for (int kd = 0; kd < 4; kd++)
          kf[kb * 4 + kd] = *(const bf16x8*)(Kb + (size_t)(k0 + 64 + kb * 32 + c) * 3072 + kd * 16 + hi * 8);
    }

    // tree max (depth 5 + 1 shuffle)
    float tm[16];
    #pragma unroll
    for (int r = 0; r < 16; r++) tm[r] = fmaxf(p[r], p[r + 16]);
    #pragma unroll
    for (int s = 8; s >= 1; s >>= 1)
      #pragma unroll
      for (int r = 0; r < s; r++) tm[r] = fmaxf(tm[r], tm[r + s]);
    float pmax = fmaxf(tm[0], __shfl_xor(tm[0], 32));

    if (__any(pmax > m_run + 8.f)){
      float m_new = fmaxf(m_run, pmax);
      float corr = EXP2(m_run - m_new);
      l_run *= corr;
      m_run = m_new;
      #pragma unroll
      for (int r = 0; r < 16; r++){
        float cr = __shfl(corr, (r & 3) + 8 * (r >> 2) + 4 * hi);
        o0[r] *= cr; o1[r] *= cr;
      }
    }

    // exp + tree sum
    float ts[16];
    #pragma unroll
    for (int r = 0; r < 16; r++){
      p[r]      = EXP2(p[r] - m_run);
      p[r + 16] = EXP2(p[r + 16] - m_run);
      ts[r] = p[r] + p[r + 16];
    }
    #pragma unroll
    for (int s = 8; s >= 1; s >>= 1)
      #pragma unroll
      for (int r = 0; r < s; r++) ts[r] += ts[r + s];
    l_run += ts[0] + __shfl_xor(ts[0], 32);

    // P -> bf16 A-frags: 16 cvt_pk + 8 permlane32_swap
    union { u32 wdw[4]; bf16x8 v; } af[4];
    #pragma unroll
    for (int ks = 0; ks < 4; ks++){
      int b0 = (ks >> 1) * 16 + 8 * (ks & 1);
      u32 c00 = cvtpk(p[b0],     p[b0 + 1]);
      u32 c01 = cvtpk(p[b0 + 2], p[b0 + 3]);
      u32 c10 = cvtpk(p[b0 + 4], p[b0 + 5]);
      u32 c11 = cvtpk(p[b0 + 6], p[b0 + 7]);
      asm volatile("v_permlane32_swap_b32 %0, %1" : "+v"(c10), "+v"(c00));
      asm volatile("v_permlane32_swap_b32 %0, %1" : "+v"(c11), "+v"(c01));
      af[ks].wdw[0] = c00; af[ks].wdw[1] = c01; af[ks].wdw[2] = c10; af[ks].wdw[3] = c11;
    }

    __builtin_amdgcn_s_setprio(1);
    #pragma unroll
    for (int ks = 0; ks < 4; ks++){
      o0 = mfma32(af[ks].v, vf[ks],     o0);
      o1 = mfma32(af[ks].v, vf[4 + ks], o1);
    }
    __builtin_amdgcn_s_setprio(0);
  }

  // epilogue: un-normalized O + (m,l)
  if (lane < 32){
    float2* mlp = (float2*)ml;
    mlp[((size_t)split * 64 + bh) * SEQ + q0 + c] = make_float2(m_run, l_run);
  }
  #pragma unroll
  for (int r = 0; r < 16; r++){
    int crow = (r & 3) + 8 * (r >> 2) + 4 * hi;
    size_t base = (size_t)split * MTOT * 1024 + (size_t)(b * SEQ + q0 + crow) * 1024 + hh * 64;
    Opart[base + c]      = o0[r];
    Opart[base + 32 + c] = o1[r];
  }
}

// ---------------- split-KV combine: ctx = (O0*w0 + O1*w1) / (l0*w0 + l1*w1) ----------------
__global__ __launch_bounds__(256) void attn_combine_kernel(
    const float* __restrict__ Opart, const float* __restrict__ ml,
    ush* __restrict__ ctx)
{
  const int row = blockIdx.x;            // b*S + q
  const int b = row >> 10, q = row & 1023;
  const int col = threadIdx.x * 4;
  const int hh = col >> 6;
  const int bh = b * 16 + hh;
  const float2* mlp = (const float2*)ml;
  float2 a0 = mlp[(size_t)bh * SEQ + q];
  float2 a1 = mlp[((size_t)64 + bh) * SEQ + q];
  float m = fmaxf(a0.x, a1.x);
  float w0 = EXP2(a0.x - m), w1 = EXP2(a1.x - m);
  float li = 1.f / fmaxf(a0.y * w0 + a1.y * w1, 1e-30f);
  size_t base = (size_t)row * 1024 + col;
  float4 u = *(const float4*)&Opart[base];
  float4 v = *(const float4*)&Opart[(size_t)MTOT * 1024 + base];
  ushort4 o;
  o.x = f2bf((u.x * w0 + v.x * w1) * li);
  o.y = f2bf((u.y * w0 + v.y * w1) * li);
  o.z = f2bf((u.z * w0 + v.z * w1) * li);
  o.w = f2bf((u.w * w0 + v.w * w1) * li);
  *(ushort4*)&ctx[base] = o;
}

// -------- residual + 4-way split-K reduce + bias + LayerNorm --------
template<bool WB>
__global__ __launch_bounds__(256) void ln4_kernel(
    const float* __restrict__ X, const float* __restrict__ P,
    const float* __restrict__ bias,
    const float* __restrict__ gam, const float* __restrict__ bet,
    float* __restrict__ Of, ush* __restrict__ Ob)
{
  const int row = blockIdx.x, tid = threadIdx.x;
  const size_t base = (size_t)row * 1024 + tid * 4;
  float4 xv = *(const float4*)&X[base];
  float4 bv4 = *(const float4*)&bias[tid * 4];
  float s0 = xv.x + bv4.x, s1 = xv.y + bv4.y, s2 = xv.z + bv4.z, s3 = xv.w + bv4.w;
  #pragma unroll
  for (int z = 0; z < 4; z++){
    float4 p = *(const float4*)&P[(size_t)z * 4194304 + base];
    s0 += p.x; s1 += p.y; s2 += p.z; s3 += p.w;
  }
  float sum = s0 + s1 + s2 + s3;
  float sq  = s0 * s0 + s1 * s1 + s2 * s2 + s3 * s3;
  #pragma unroll
  for (int o = 1; o < 64; o <<= 1){ sum += __shfl_xor(sum, o); sq += __shfl_xor(sq, o); }
  __shared__ float red[8];
  int lane = tid & 63, w = tid >> 6;
  if (lane == 0){ red[w] = sum; red[4 + w] = sq; }
  __syncthreads();
  sum = red[0] + red[1] + red[2] + red[3];
  sq  = red[4] + red[5] + red[6] + red[7];
  float mean = sum * (1.f / 1024.f);
  float var  = sq * (1.f / 1024.f) - mean * mean;
  float rs = rsqrtf(var + 1e-5f);
  float4 gv = *(const float4*)&gam[tid * 4];
  float4 bt = *(const float4*)&bet[tid * 4];
  float o0 = (s0 - mean) * rs * gv.x + bt.x;
  float o1 = (s1 - mean) * rs * gv.y + bt.y;
  float o2 = (s2 - mean) * rs * gv.z + bt.z;
  float o3 = (s3 - mean) * rs * gv.w + bt.w;
  float4 ov = { o0, o1, o2, o3 };
  *(float4*)&Of[base] = ov;
  if (WB){
    ushort4 ob = { f2bf(o0), f2bf(o1), f2bf(o2), f2bf(o3) };
    *(ushort4*)&Ob[base] = ob;
  }
}

// ---------------- orchestration ----------------
extern "C" void kernel_launch(void* const* d_in, const int* in_sizes, int n_in,
                              void* d_out, int out_size, void* d_ws, size_t ws_size,
                              hipStream_t stream)
{
  const float* x    = (const float*)d_in[0];
  const int*   mask = (const int*)  d_in[1];
  const float* Wq = (const float*)d_in[2];
  const float* bq = (const float*)d_in[3];
  const float* Wk = (const float*)d_in[4];
  const float* bk = (const float*)d_in[5];
  const float* Wv = (const float*)d_in[6];
  const float* bv = (const float*)d_in[7];
  const float* Wo = (const float*)d_in[8];
  const float* bo = (const float*)d_in[9];
  const float* W1 = (const float*)d_in[10];
  const float* b1 = (const float*)d_in[11];
  const float* W2 = (const float*)d_in[12];
  const float* b2 = (const float*)d_in[13];
  const float* g1 = (const float*)d_in[14];
  const float* be1= (const float*)d_in[15];
  const float* g2 = (const float*)d_in[16];
  const float* be2= (const float*)d_in[17];
  float* out = (float*)d_out;

  char* ws = (char*)d_ws;
  size_t off = 0;
  auto alloc = [&](size_t bytes)->void*{ void* p = ws + off; off += (bytes + 255) & ~(size_t)255; return p; };
  ush* xb     = (ush*)alloc((size_t)MTOT * 1024 * 2);
  ush* wqkvT  = (ush*)alloc((size_t)3072 * 1024 * 2);
  ush* woT    = (ush*)alloc((size_t)1024 * 1024 * 2);
  ush* w1T    = (ush*)alloc((size_t)4096 * 1024 * 2);
  ush* w2T    = (ush*)alloc((size_t)1024 * 4096 * 2);
  float* bqkv = (float*)alloc(3072 * 4);
  ush* qkv    = (ush*)alloc((size_t)MTOT * 3072 * 2);   // reused (with ctx) as ff1
  ush* ctx    = (ush*)alloc((size_t)MTOT * 1024 * 2);
  float* part = (float*)alloc((size_t)4 * MTOT * 1024 * 4);  // split-K partials (64MB)
  float* h    = (float*)alloc((size_t)MTOT * 1024 * 4);
  ush* hb     = (ush*)alloc((size_t)MTOT * 1024 * 2);
  ush* VT     = (ush*)alloc((size_t)64 * 64 * SEQ * 2);      // V^T per (b,h)
  ush* ff1    = qkv;   // 32 MB span (qkv 24MB + ctx 8MB), both dead by then
  // attention split-KV scratch aliases onto `part` (dead until Wo GEMM):
  float* Opart = part;                                        // 32 MB (2 splits)
  float* mlbuf = part + (size_t)2 * MTOT * 1024;              // 1 MB

  // 1. converts / transposes
  cvt_kernel<<<dim3(4096), dim3(256), 0, stream>>>(x, xb, MTOT * 1024);
  tconv_kernel<<<dim3(32, 32), dim3(256), 0, stream>>>(Wq, wqkvT,               1024, 1024);
  tconv_kernel<<<dim3(32, 32), dim3(256), 0, stream>>>(Wk, wqkvT + 1024 * 1024, 1024, 1024);
  tconv_kernel<<<dim3(32, 32), dim3(256), 0, stream>>>(Wv, wqkvT + 2048 * 1024, 1024, 1024);
  tconv_kernel<<<dim3(32, 32), dim3(256), 0, stream>>>(Wo, woT,                 1024, 1024);
  tconv_kernel<<<dim3(128, 32), dim3(256), 0, stream>>>(W1, w1T, 1024, 4096);
  tconv_kernel<<<dim3(32, 128), dim3(256), 0, stream>>>(W2, w2T, 4096, 1024);
  biaspack_kernel<<<dim3(12), dim3(256), 0, stream>>>(bq, bk, bv, bqkv);

  // 2. QKV projection (Q pre-scaled by log2e/8 in epilogue)
  gemm8_kernel<0, 0, 1><<<dim3(12, 16, 1), dim3(512), 0, stream>>>(
      xb, wqkvT, bqkv, qkv, nullptr, MTOT, 3072, 1024, 3072, 1024);

  // 3. V transpose for attention B-frags
  vtrans_kernel<<<dim3(32, 2, 64), dim3(256), 0, stream>>>(qkv, VT);

  // 4. attention (split-KV x2) -> Opart/ml, then combine -> ctx
  attn2_kernel<<<dim3(8, 2, 64), dim3(256), 0, stream>>>(qkv, VT, mask, Opart, mlbuf);
  attn_combine_kernel<<<dim3(4096), dim3(256), 0, stream>>>(Opart, mlbuf, ctx);

  // 5. Wo partials: split-K=4, f32 [4][4096][1024]
  gemm8_kernel<0, 1, 0><<<dim3(4, 16, 4), dim3(512), 0, stream>>>(
      ctx, woT, nullptr, nullptr, part, MTOT, 1024, 1024, 1024, 256);

  // 6. h = LN(x + sum(part) + bo)
  ln4_kernel<true><<<dim3(4096), dim3(256), 0, stream>>>(x, part, bo, g1, be1, h, hb);

  // 7. ff1 = relu(h @ W1 + b1) bf16 [4096,4096]
  gemm8_kernel<1, 0, 0><<<dim3(16, 16, 1), dim3(512), 0, stream>>>(
      hb, w1T, b1, ff1, nullptr, MTOT, 4096, 1024, 4096, 1024);

  // 8. FF2 partials: split-K=4 over K=4096
  gemm8_kernel<0, 1, 0><<<dim3(4, 16, 4), dim3(512), 0, stream>>>(
      ff1, w2T, nullptr, nullptr, part, MTOT, 1024, 4096, 1024, 1024);

  // 9. out = LN(h + sum(part) + b2)
  ln4_kernel<false><<<dim3(4096), dim3(256), 0, stream>>>(h, part, b2, g2, be2, out, nullptr);
}

// Round 6
// 395.743 us; speedup vs baseline: 1.2262x; 1.0608x over previous
//
#include <hip/hip_runtime.h>
#include <hip/hip_bf16.h>

typedef __attribute__((ext_vector_type(8))) short bf16x8;
typedef __attribute__((ext_vector_type(4))) float f32x4;
typedef __attribute__((ext_vector_type(16))) float f32x16;
typedef unsigned int u32;
typedef unsigned short ush;

#define SEQ 1024
#define MTOT 4096   // B*S
#define QSCALE_LOG2 0.18033688f   // log2(e)/8

#if __has_builtin(__builtin_amdgcn_exp2f)
#define EXP2(x) __builtin_amdgcn_exp2f(x)
#else
#define EXP2(x) exp2f(x)
#endif

__device__ __forceinline__ ush f2bf(float f){
  u32 u = __float_as_uint(f);
  u32 r = (u + 0x7fffu + ((u >> 16) & 1u)) >> 16;
  return (ush)r;
}

__device__ __forceinline__ f32x4 mfma16(bf16x8 a, bf16x8 b, f32x4 c){
  return __builtin_amdgcn_mfma_f32_16x16x32_bf16(a, b, c, 0, 0, 0);
}
__device__ __forceinline__ f32x16 mfma32(bf16x8 a, bf16x8 b, f32x16 c){
  return __builtin_amdgcn_mfma_f32_32x32x16_bf16(a, b, c, 0, 0, 0);
}

__device__ __forceinline__ u32 cvtpk(float lo, float hi){
  u32 r; asm("v_cvt_pk_bf16_f32 %0, %1, %2" : "=v"(r) : "v"(lo), "v"(hi)); return r;
}

__device__ __forceinline__ void gload_lds16(const ush* g, ush* l){
  __builtin_amdgcn_global_load_lds(
      (const __attribute__((address_space(1))) u32*)g,
      (__attribute__((address_space(3))) u32*)l, 16, 0, 0);
}

// ---------------- elementwise convert f32 -> bf16 ----------------
__global__ __launch_bounds__(256) void cvt_kernel(const float* __restrict__ src,
                                                  ush* __restrict__ dst, int n){
  int i = (blockIdx.x * 256 + threadIdx.x) * 4;
  if (i < n){
    float4 v = *(const float4*)&src[i];
    ushort4 o = { f2bf(v.x), f2bf(v.y), f2bf(v.z), f2bf(v.w) };
    *(ushort4*)&dst[i] = o;
  }
}

// ---------------- transpose + convert: dst[c][r] = bf16(src[r][c]) ----------------
__global__ __launch_bounds__(256) void tconv_kernel(const float* __restrict__ src,
                                                    ush* __restrict__ dst, int R, int C){
  __shared__ float t[32][33];
  int tx = threadIdx.x & 31, ty = threadIdx.x >> 5;
  int r0 = blockIdx.y * 32, c0 = blockIdx.x * 32;
  #pragma unroll
  for (int i = 0; i < 32; i += 8)
    t[ty + i][tx] = src[(size_t)(r0 + ty + i) * C + (c0 + tx)];
  __syncthreads();
  #pragma unroll
  for (int i = 0; i < 32; i += 8)
    dst[(size_t)(c0 + ty + i) * R + (r0 + tx)] = f2bf(t[tx][ty + i]);
}

__global__ __launch_bounds__(256) void biaspack_kernel(const float* __restrict__ bq,
    const float* __restrict__ bk, const float* __restrict__ bv, float* __restrict__ dst){
  int i = blockIdx.x * 256 + threadIdx.x;
  if (i < 3072){
    float v = (i < 1024) ? bq[i] : (i < 2048) ? bk[i - 1024] : bv[i - 2048];
    dst[i] = v;
  }
}

// ---------------- V transpose: VT[bh*64+d][key] = qkv[b*S+key][2048+h*64+d] ----------------
__global__ __launch_bounds__(256) void vtrans_kernel(const ush* __restrict__ qkv,
                                                     ush* __restrict__ VT){
  __shared__ ush t[32][34];
  int tx = threadIdx.x & 31, ty = threadIdx.x >> 5;   // ty 0..7
  int bh = blockIdx.z, b = bh >> 4, h = bh & 15;
  int k0 = blockIdx.x * 32, d0 = blockIdx.y * 32;
  #pragma unroll
  for (int i = 0; i < 32; i += 8)
    t[ty + i][tx] = qkv[(size_t)(b * SEQ + k0 + ty + i) * 3072 + 2048 + h * 64 + d0 + tx];
  __syncthreads();
  #pragma unroll
  for (int i = 0; i < 32; i += 8)
    VT[(size_t)(bh * 64 + d0 + ty + i) * SEQ + k0 + tx] = t[tx][ty + i];
}

// =====================================================================
// 256x256 8-phase GEMM (unchanged from round 3)
// =====================================================================
__device__ __forceinline__ void stage_piece(ush* piece, const ush* g0, int K,
                                            int tid, int w){
  #pragma unroll
  for (int I = 0; I < 2; I++){
    int c = I * 512 + tid;
    int r = c >> 2;
    int gl = (c & 3) ^ ((r >> 1) & 3);
    gload_lds16(g0 + (size_t)r * K + gl * 8, piece + I * 4096 + w * 512);
  }
}

__device__ __forceinline__ bf16x8 frag(const ush* piece, int row, int g){
  int phys = g ^ ((row >> 1) & 3);
  return *(const bf16x8*)(piece + row * 32 + phys * 8);
}

#define PH_BAR_TOP() do{ __builtin_amdgcn_sched_barrier(0); \
  __builtin_amdgcn_s_barrier(); \
  asm volatile("s_waitcnt lgkmcnt(0)" ::: "memory"); \
  __builtin_amdgcn_sched_barrier(0); \
  __builtin_amdgcn_s_setprio(1); }while(0)
#define PH_BAR_BOT() do{ __builtin_amdgcn_s_setprio(0); \
  __builtin_amdgcn_sched_barrier(0); \
  __builtin_amdgcn_s_barrier(); }while(0)

template<int RELU, int OUTF32, int SCALEQ>
__global__ __launch_bounds__(512, 2) void gemm8_kernel(
    const ush* __restrict__ A, const ush* __restrict__ Bt,
    const float* __restrict__ bias,
    ush* __restrict__ Cb, float* __restrict__ Cf,
    int M, int N, int K, int ldc, int ksl)
{
  __shared__ ush lds[2][2][2][8192];   // [buf][A/B][ks][16KB piece]
  const int tid = threadIdx.x;
  const int lane = tid & 63, w = tid >> 6;
  const int g = lane >> 4, qr = lane & 15;
  const int wr = w >> 2, wc = w & 3;
  const int gx = gridDim.x;
  const int nwg = gx * gridDim.y;
  const int id = blockIdx.y * gx + blockIdx.x;
  const int swz = (id & 7) * (nwg >> 3) + (id >> 3);
  const int bn = (swz % gx) * 256;
  const int bm = (swz / gx) * 256;
  const int kbase = blockIdx.z * ksl;
  const int NT = ksl >> 6;
  const ush* Ab = A  + (size_t)bm * K + kbase;
  const ush* Bb = Bt + (size_t)bn * K + kbase;

  stage_piece(lds[0][0][0], Ab,      K, tid, w);
  stage_piece(lds[0][1][0], Bb,      K, tid, w);
  stage_piece(lds[0][0][1], Ab + 32, K, tid, w);
  stage_piece(lds[0][1][1], Bb + 32, K, tid, w);
  if (NT > 1){
    stage_piece(lds[1][0][0], Ab + 64, K, tid, w);
    stage_piece(lds[1][1][0], Bb + 64, K, tid, w);
  }
  asm volatile("s_waitcnt vmcnt(4)" ::: "memory");
  __builtin_amdgcn_sched_barrier(0);
  __builtin_amdgcn_s_barrier();

  f32x4 acc[8][4] = {};
  const int ar = wr * 128 + qr;
  const int br = wc * 64 + qr;

  for (int T = 0; T < NT; ++T){
    const int cb = T & 1, nb = cb ^ 1;
    const ush* An = Ab + (size_t)(T + 1) * 64;
    const ush* Bn = Bb + (size_t)(T + 1) * 64;
    const ush* Af = Ab + (size_t)(T + 2) * 64;
    const ush* Bf = Bb + (size_t)(T + 2) * 64;
    bf16x8 af[4], bfr[4];

    #pragma unroll
    for (int j = 0; j < 4; j++) bfr[j] = frag(lds[cb][1][0], br + j * 16, g);
    #pragma unroll
    for (int i = 0; i < 4; i++) af[i] = frag(lds[cb][0][0], ar + i * 16, g);
    if (T + 1 < NT) stage_piece(lds[nb][0][1], An + 32, K, tid, w);
    PH_BAR_TOP();
    #pragma unroll
    for (int i = 0; i < 4; i++)
      #pragma unroll
      for (int j = 0; j < 4; j++)
        acc[i][j] = mfma16(af[i], bfr[j], acc[i][j]);
    PH_BAR_BOT();

    #pragma unroll
    for (int i = 0; i < 4; i++) af[i] = frag(lds[cb][0][0], ar + 64 + i * 16, g);
    if (T + 1 < NT) stage_piece(lds[nb][1][1], Bn + 32, K, tid, w);
    PH_BAR_TOP();
    #pragma unroll
    for (int i = 0; i < 4; i++)
      #pragma unroll
      for (int j = 0; j < 4; j++)
        acc[4 + i][j] = mfma16(af[i], bfr[j], acc[4 + i][j]);
    PH_BAR_BOT();

    #pragma unroll
    for (int j = 0; j < 4; j++) bfr[j] = frag(lds[cb][1][1], br + j * 16, g);
    #pragma unroll
    for (int i = 0; i < 4; i++) af[i] = frag(lds[cb][0][1], ar + i * 16, g);
    if (T + 2 < NT) stage_piece(lds[cb][0][0], Af, K, tid, w);
    PH_BAR_TOP();
    #pragma unroll
    for (int i = 0; i < 4; i++)
      #pragma unroll
      for (int j = 0; j < 4; j++)
        acc[i][j] = mfma16(af[i], bfr[j], acc[i][j]);
    PH_BAR_BOT();

    #pragma unroll
    for (int i = 0; i < 4; i++) af[i] = frag(lds[cb][0][1], ar + 64 + i * 16, g);
    if (T + 2 < NT) stage_piece(lds[cb][1][0], Bf, K, tid, w);
    PH_BAR_TOP();
    #pragma unroll
    for (int i = 0; i < 4; i++)
      #pragma unroll
      for (int j = 0; j < 4; j++)
        acc[4 + i][j] = mfma16(af[i], bfr[j], acc[4 + i][j]);
    __builtin_amdgcn_s_setprio(0);
    __builtin_amdgcn_sched_barrier(0);
    asm volatile("s_waitcnt vmcnt(4)" ::: "memory");
    __builtin_amdgcn_sched_barrier(0);
    __builtin_amdgcn_s_barrier();
  }

  float* Cfz = Cf;
  if (OUTF32) Cfz = Cf + (size_t)blockIdx.z * M * ldc;
  #pragma unroll
  for (int j = 0; j < 4; j++){
    const int col = bn + wc * 64 + j * 16 + qr;
    const float bv = OUTF32 ? 0.f : bias[col];
    const float scl = (SCALEQ && col < 1024) ? QSCALE_LOG2 : 1.f;
    #pragma unroll
    for (int i = 0; i < 8; i++){
      const int row0 = bm + wr * 128 + i * 16 + g * 4;
      #pragma unroll
      for (int rr = 0; rr < 4; rr++){
        float v = acc[i][j][rr] + bv;
        if (RELU) v = fmaxf(v, 0.f);
        if (SCALEQ) v *= scl;
        const size_t idx = (size_t)(row0 + rr) * ldc + col;
        if (OUTF32) Cfz[idx] = v; else Cb[idx] = f2bf(v);
      }
    }
  }
}

// =====================================================================
// Flash attention v4: intra-block KV-split x2, LDS merge, 32x32x16 MFMA,
// swapped QK^T, in-register softmax (tree reduce + cvt_pk + permlane32_swap),
// exp2 domain. grid: (S/64, B*H), block 256 = 2 q-groups x 2 kv-splits.
// No launch_bounds min-wave clamp: R3 proved this body allocates 128 VGPR
// spill-free; 4 blocks/CU (LDS 36KB) = 16 waves/CU.
// =====================================================================
__global__ __launch_bounds__(256) void attn2_kernel(
    const ush* __restrict__ qkv, const ush* __restrict__ VT,
    const int* __restrict__ mask, ush* __restrict__ ctx)
{
  __shared__ float Ocomb[2][2][32][68];   // [qgroup][split][row][col(64)+pad]
  __shared__ float mlsh[2][2][2][32];     // [qgroup][split][m/l][q]
  __shared__ int mflag;

  const int tid = threadIdx.x;
  const int lane = tid & 63, w = tid >> 6;
  const int c = lane & 31, hi = lane >> 5;
  const int wq = w >> 1, ws = w & 1;
  const int bh = blockIdx.y, b = bh >> 4, hh = bh & 15;
  const int kbeg = ws * 512;
  const int q0 = blockIdx.x * 64 + wq * 32;

  if (tid == 0) mflag = 1;
  __syncthreads();
  {
    int4 mv = *(const int4*)&mask[b * SEQ + tid * 4];
    if (!(mv.x && mv.y && mv.z && mv.w)) mflag = 0;
  }
  __syncthreads();
  const bool maskall = (mflag != 0);

  const ush* Qrow = qkv + (size_t)(b * SEQ + q0 + c) * 3072 + hh * 64;
  bf16x8 qf[4];
  #pragma unroll
  for (int kd = 0; kd < 4; kd++)
    qf[kd] = *(const bf16x8*)(Qrow + kd * 16 + hi * 8);

  const ush* Kb  = qkv + (size_t)(b * SEQ) * 3072 + 1024 + hh * 64;
  const ush* VTb = VT + (size_t)(bh * 64) * SEQ;

  f32x16 o0 = {}, o1 = {};
  float m_run = -1e30f, l_run = 0.f;

  bf16x8 kf[8];
  #pragma unroll
  for (int kb = 0; kb < 2; kb++)
    #pragma unroll
    for (int kd = 0; kd < 4; kd++)
      kf[kb * 4 + kd] = *(const bf16x8*)(Kb + (size_t)(kbeg + kb * 32 + c) * 3072 + kd * 16 + hi * 8);

  for (int t = 0; t < 8; ++t){
    const int k0 = kbeg + t * 64;
    bf16x8 vf[8];
    #pragma unroll
    for (int db = 0; db < 2; db++)
      #pragma unroll
      for (int ks = 0; ks < 4; ks++)
        vf[db * 4 + ks] = *(const bf16x8*)(VTb + (size_t)(db * 32 + c) * SEQ + k0 + ks * 16 + hi * 8);

    f32x16 s0 = {}, s1 = {};
    __builtin_amdgcn_s_setprio(1);
    #pragma unroll
    for (int kd = 0; kd < 4; kd++){
      s0 = mfma32(kf[kd],     qf[kd], s0);
      s1 = mfma32(kf[4 + kd], qf[kd], s1);
    }
    __builtin_amdgcn_s_setprio(0);

    float p[32];
    #pragma unroll
    for (int r = 0; r < 16; r++){ p[r] = s0[r]; p[16 + r] = s1[r]; }

    if (!maskall){
      #pragma unroll
      for (int r32 = 0; r32 < 32; r32++){
        int r = r32 & 15;
        int key = (r32 >> 4) * 32 + (r & 3) + 8 * (r >> 2) + 4 * hi;
        if (mask[b * SEQ + k0 + key] == 0) p[r32] = -1e9f;
      }
    }

    // prefetch K frags for next tile (lands under softmax)
    if (t + 1 < 8){
      #pragma unroll
      for (int kb = 0; kb < 2; kb++)
        #pragma unroll
        for (int kd = 0; kd < 4; kd++)
          kf[kb * 4 + kd] = *(const bf16x8*)(Kb + (size_t)(k0 + 64 + kb * 32 + c) * 3072 + kd * 16 + hi * 8);
    }

    // tree max (depth 5 + 1 shuffle)
    float tm[16];
    #pragma unroll
    for (int r = 0; r < 16; r++) tm[r] = fmaxf(p[r], p[r + 16]);
    #pragma unroll
    for (int s = 8; s >= 1; s >>= 1)
      #pragma unroll
      for (int r = 0; r < s; r++) tm[r] = fmaxf(tm[r], tm[r + s]);
    float pmax = fmaxf(tm[0], __shfl_xor(tm[0], 32));

    if (__any(pmax > m_run + 8.f)){
      float m_new = fmaxf(m_run, pmax);
      float corr = EXP2(m_run - m_new);
      l_run *= corr;
      m_run = m_new;
      #pragma unroll
      for (int r = 0; r < 16; r++){
        float cr = __shfl(corr, (r & 3) + 8 * (r >> 2) + 4 * hi);
        o0[r] *= cr; o1[r] *= cr;
      }
    }

    // exp + tree sum
    float ts[16];
    #pragma unroll
    for (int r = 0; r < 16; r++){
      p[r]      = EXP2(p[r] - m_run);
      p[r + 16] = EXP2(p[r + 16] - m_run);
      ts[r] = p[r] + p[r + 16];
    }
    #pragma unroll
    for (int s = 8; s >= 1; s >>= 1)
      #pragma unroll
      for (int r = 0; r < s; r++) ts[r] += ts[r + s];
    l_run += ts[0] + __shfl_xor(ts[0], 32);

    // P -> bf16 A-frags: 16 cvt_pk + 8 permlane32_swap
    union { u32 wdw[4]; bf16x8 v; } af[4];
    #pragma unroll
    for (int ks = 0; ks < 4; ks++){
      int b0 = (ks >> 1) * 16 + 8 * (ks & 1);
      u32 c00 = cvtpk(p[b0],     p[b0 + 1]);
      u32 c01 = cvtpk(p[b0 + 2], p[b0 + 3]);
      u32 c10 = cvtpk(p[b0 + 4], p[b0 + 5]);
      u32 c11 = cvtpk(p[b0 + 6], p[b0 + 7]);
      asm volatile("v_permlane32_swap_b32 %0, %1" : "+v"(c10), "+v"(c00));
      asm volatile("v_permlane32_swap_b32 %0, %1" : "+v"(c11), "+v"(c01));
      af[ks].wdw[0] = c00; af[ks].wdw[1] = c01; af[ks].wdw[2] = c10; af[ks].wdw[3] = c11;
    }

    __builtin_amdgcn_s_setprio(1);
    #pragma unroll
    for (int ks = 0; ks < 4; ks++){
      o0 = mfma32(af[ks].v, vf[ks],     o0);
      o1 = mfma32(af[ks].v, vf[4 + ks], o1);
    }
    __builtin_amdgcn_s_setprio(0);
  }

  // ---- intra-block combine through LDS ----
  if (lane < 32){
    mlsh[wq][ws][0][c] = m_run;
    mlsh[wq][ws][1][c] = l_run;
  }
  #pragma unroll
  for (int r = 0; r < 16; r++){
    int crow = (r & 3) + 8 * (r >> 2) + 4 * hi;
    Ocomb[wq][ws][crow][c]      = o0[r];
    Ocomb[wq][ws][crow][32 + c] = o1[r];
  }
  __syncthreads();

  // merge: this warp handles rows 0..31 of q-group wq, cols [ws*32+hi*16, +16)
  {
    const int r2 = c;                    // row within q-group
    const int cbase = ws * 32 + hi * 16; // 16 cols per lane
    float m0 = mlsh[wq][0][0][r2], l0 = mlsh[wq][0][1][r2];
    float m1 = mlsh[wq][1][0][r2], l1 = mlsh[wq][1][1][r2];
    float m  = fmaxf(m0, m1);
    float w0 = EXP2(m0 - m), w1 = EXP2(m1 - m);
    float li = 1.f / fmaxf(l0 * w0 + l1 * w1, 1e-30f);
    size_t gbase = (size_t)(b * SEQ + q0 + r2) * 1024 + hh * 64 + cbase;
    #pragma unroll
    for (int cc = 0; cc < 16; cc += 4){
      float4 u = *(const float4*)&Ocomb[wq][0][r2][cbase + cc];
      float4 v = *(const float4*)&Ocomb[wq][1][r2][cbase + cc];
      ushort4 ob;
      ob.x = f2bf((u.x * w0 + v.x * w1) * li);
      ob.y = f2bf((u.y * w0 + v.y * w1) * li);
      ob.z = f2bf((u.z * w0 + v.z * w1) * li);
      ob.w = f2bf((u.w * w0 + v.w * w1) * li);
      *(ushort4*)&ctx[gbase + cc] = ob;
    }
  }
}

// -------- residual + 4-way split-K reduce + bias + LayerNorm --------
template<bool WB>
__global__ __launch_bounds__(256) void ln4_kernel(
    const float* __restrict__ X, const float* __restrict__ P,
    const float* __restrict__ bias,
    const float* __restrict__ gam, const float* __restrict__ bet,
    float* __restrict__ Of, ush* __restrict__ Ob)
{
  const int row = blockIdx.x, tid = threadIdx.x;
  const size_t base = (size_t)row * 1024 + tid * 4;
  float4 xv = *(const float4*)&X[base];
  float4 bv4 = *(const float4*)&bias[tid * 4];
  float s0 = xv.x + bv4.x, s1 = xv.y + bv4.y, s2 = xv.z + bv4.z, s3 = xv.w + bv4.w;
  #pragma unroll
  for (int z = 0; z < 4; z++){
    float4 p = *(const float4*)&P[(size_t)z * 4194304 + base];
    s0 += p.x; s1 += p.y; s2 += p.z; s3 += p.w;
  }
  float sum = s0 + s1 + s2 + s3;
  float sq  = s0 * s0 + s1 * s1 + s2 * s2 + s3 * s3;
  #pragma unroll
  for (int o = 1; o < 64; o <<= 1){ sum += __shfl_xor(sum, o); sq += __shfl_xor(sq, o); }
  __shared__ float red[8];
  int lane = tid & 63, w = tid >> 6;
  if (lane == 0){ red[w] = sum; red[4 + w] = sq; }
  __syncthreads();
  sum = red[0] + red[1] + red[2] + red[3];
  sq  = red[4] + red[5] + red[6] + red[7];
  float mean = sum * (1.f / 1024.f);
  float var  = sq * (1.f / 1024.f) - mean * mean;
  float rs = rsqrtf(var + 1e-5f);
  float4 gv = *(const float4*)&gam[tid * 4];
  float4 bt = *(const float4*)&bet[tid * 4];
  float o0 = (s0 - mean) * rs * gv.x + bt.x;
  float o1 = (s1 - mean) * rs * gv.y + bt.y;
  float o2 = (s2 - mean) * rs * gv.z + bt.z;
  float o3 = (s3 - mean) * rs * gv.w + bt.w;
  float4 ov = { o0, o1, o2, o3 };
  *(float4*)&Of[base] = ov;
  if (WB){
    ushort4 ob = { f2bf(o0), f2bf(o1), f2bf(o2), f2bf(o3) };
    *(ushort4*)&Ob[base] = ob;
  }
}

// ---------------- orchestration ----------------
extern "C" void kernel_launch(void* const* d_in, const int* in_sizes, int n_in,
                              void* d_out, int out_size, void* d_ws, size_t ws_size,
                              hipStream_t stream)
{
  const float* x    = (const float*)d_in[0];
  const int*   mask = (const int*)  d_in[1];
  const float* Wq = (const float*)d_in[2];
  const float* bq = (const float*)d_in[3];
  const float* Wk = (const float*)d_in[4];
  const float* bk = (const float*)d_in[5];
  const float* Wv = (const float*)d_in[6];
  const float* bv = (const float*)d_in[7];
  const float* Wo = (const float*)d_in[8];
  const float* bo = (const float*)d_in[9];
  const float* W1 = (const float*)d_in[10];
  const float* b1 = (const float*)d_in[11];
  const float* W2 = (const float*)d_in[12];
  const float* b2 = (const float*)d_in[13];
  const float* g1 = (const float*)d_in[14];
  const float* be1= (const float*)d_in[15];
  const float* g2 = (const float*)d_in[16];
  const float* be2= (const float*)d_in[17];
  float* out = (float*)d_out;

  char* ws = (char*)d_ws;
  size_t off = 0;
  auto alloc = [&](size_t bytes)->void*{ void* p = ws + off; off += (bytes + 255) & ~(size_t)255; return p; };
  ush* xb     = (ush*)alloc((size_t)MTOT * 1024 * 2);
  ush* wqkvT  = (ush*)alloc((size_t)3072 * 1024 * 2);
  ush* woT    = (ush*)alloc((size_t)1024 * 1024 * 2);
  ush* w1T    = (ush*)alloc((size_t)4096 * 1024 * 2);
  ush* w2T    = (ush*)alloc((size_t)1024 * 4096 * 2);
  float* bqkv = (float*)alloc(3072 * 4);
  ush* qkv    = (ush*)alloc((size_t)MTOT * 3072 * 2);   // reused (with ctx) as ff1
  ush* ctx    = (ush*)alloc((size_t)MTOT * 1024 * 2);
  float* part = (float*)alloc((size_t)4 * MTOT * 1024 * 4);  // split-K partials (64MB)
  float* h    = (float*)alloc((size_t)MTOT * 1024 * 4);
  ush* hb     = (ush*)alloc((size_t)MTOT * 1024 * 2);
  ush* VT     = (ush*)alloc((size_t)64 * 64 * SEQ * 2);      // V^T per (b,h)
  ush* ff1    = qkv;   // 32 MB span (qkv 24MB + ctx 8MB), both dead by then

  // 1. converts / transposes
  cvt_kernel<<<dim3(4096), dim3(256), 0, stream>>>(x, xb, MTOT * 1024);
  tconv_kernel<<<dim3(32, 32), dim3(256), 0, stream>>>(Wq, wqkvT,               1024, 1024);
  tconv_kernel<<<dim3(32, 32), dim3(256), 0, stream>>>(Wk, wqkvT + 1024 * 1024, 1024, 1024);
  tconv_kernel<<<dim3(32, 32), dim3(256), 0, stream>>>(Wv, wqkvT + 2048 * 1024, 1024, 1024);
  tconv_kernel<<<dim3(32, 32), dim3(256), 0, stream>>>(Wo, woT,                 1024, 1024);
  tconv_kernel<<<dim3(128, 32), dim3(256), 0, stream>>>(W1, w1T, 1024, 4096);
  tconv_kernel<<<dim3(32, 128), dim3(256), 0, stream>>>(W2, w2T, 4096, 1024);
  biaspack_kernel<<<dim3(12), dim3(256), 0, stream>>>(bq, bk, bv, bqkv);

  // 2. QKV projection (Q pre-scaled by log2e/8 in epilogue)
  gemm8_kernel<0, 0, 1><<<dim3(12, 16, 1), dim3(512), 0, stream>>>(
      xb, wqkvT, bqkv, qkv, nullptr, MTOT, 3072, 1024, 3072, 1024);

  // 3. V transpose for attention B-frags
  vtrans_kernel<<<dim3(32, 2, 64), dim3(256), 0, stream>>>(qkv, VT);

  // 4. attention (intra-block split-KV x2) -> ctx bf16 [4096,1024]
  attn2_kernel<<<dim3(16, 64), dim3(256), 0, stream>>>(qkv, VT, mask, ctx);

  // 5. Wo partials: split-K=4, f32 [4][4096][1024]
  gemm8_kernel<0, 1, 0><<<dim3(4, 16, 4), dim3(512), 0, stream>>>(
      ctx, woT, nullptr, nullptr, part, MTOT, 1024, 1024, 1024, 256);

  // 6. h = LN(x + sum(part) + bo)
  ln4_kernel<true><<<dim3(4096), dim3(256), 0, stream>>>(x, part, bo, g1, be1, h, hb);

  // 7. ff1 = relu(h @ W1 + b1) bf16 [4096,4096]
  gemm8_kernel<1, 0, 0><<<dim3(16, 16, 1), dim3(512), 0, stream>>>(
      hb, w1T, b1, ff1, nullptr, MTOT, 4096, 1024, 4096, 1024);

  // 8. FF2 partials: split-K=4 over K=4096
  gemm8_kernel<0, 1, 0><<<dim3(4, 16, 4), dim3(512), 0, stream>>>(
      ff1, w2T, nullptr, nullptr, part, MTOT, 1024, 4096, 1024, 1024);

  // 9. out = LN(h + sum(part) + b2)
  ln4_kernel<false><<<dim3(4096), dim3(256), 0, stream>>>(h, part, b2, g2, be2, out, nullptr);
}